// Round 4
// baseline (274.473 us; speedup 1.0000x reference)
//
#include <hip/hip_runtime.h>
#include <hip/hip_bf16.h>

typedef float f32x4 __attribute__((ext_vector_type(4)));
typedef __bf16 bf16x8 __attribute__((ext_vector_type(8)));
typedef unsigned short ushort4v __attribute__((ext_vector_type(4)));
typedef unsigned short ushort8v __attribute__((ext_vector_type(8)));

#define MFMA16(a, b, c) __builtin_amdgcn_mfma_f32_16x16x32_bf16((a), (b), (c), 0, 0, 0)

__device__ __forceinline__ unsigned short f2bf(float f) {
    union { float f; unsigned int u; } v; v.f = f;
    unsigned int r = (v.u + 0x7fffu + ((v.u >> 16) & 1u)) >> 16;  // RNE
    return (unsigned short)r;
}
__device__ __forceinline__ int imin(int a, int b) { return a < b ? a : b; }

// LDS-only barrier: flush this wave's LDS ops, then s_barrier.
// Does NOT drain vmcnt -> global prefetches stay in flight across it.
__device__ __forceinline__ void ldsbar() {
    asm volatile("s_waitcnt lgkmcnt(0)" ::: "memory");
    __builtin_amdgcn_s_barrier();
}

// ---------------------------------------------------------------------------
// E -> bf16 conversion (one pass).
// ---------------------------------------------------------------------------
__global__ __launch_bounds__(256) void conv_kernel(const float* __restrict__ E,
                                                   unsigned short* __restrict__ Eb)
{
    const size_t i = ((size_t)blockIdx.x * 256 + threadIdx.x) * 8;
    f32x4 a = *(const f32x4*)&E[i];
    f32x4 b = *(const f32x4*)&E[i + 4];
    ushort8v u;
#pragma unroll
    for (int j = 0; j < 4; ++j) { u[j] = f2bf(a[j]); u[4 + j] = f2bf(b[j]); }
    *(ushort8v*)&Eb[i] = u;
}

// ---------------------------------------------------------------------------
// Projection GEMM body. M=16384, K=512. BM=128 x BN, BK=32; 4 waves (2x2).
// ---------------------------------------------------------------------------
template <int NC, int BN, bool TRV, bool BF16A>
__device__ __forceinline__ void proj_body(const void* __restrict__ Ein,
                                          const float* __restrict__ W,
                                          const float* __restrict__ bias,
                                          unsigned short* __restrict__ out,
                                          float scale, int bx, int by)
{
    constexpr int NB = BN / 32;
    constexpr int CPW = BN / 4;
    constexpr int KROWS = 256 / CPW;
    constexpr int BI = 32 / KROWS;

    __shared__ __align__(16) unsigned short Al[128][40];
    __shared__ __align__(16) unsigned short Bl[BN][40];

    const int tid = threadIdx.x;
    const int w = tid >> 6, l = tid & 63, g = l >> 4, li = l & 15;
    const int wm = w >> 1, wn = w & 1;
    const int row0 = bx * 128;
    const int c0 = by * BN;

    f32x4 acc[4][NB];
#pragma unroll
    for (int mb = 0; mb < 4; ++mb)
#pragma unroll
        for (int nb = 0; nb < NB; ++nb) acc[mb][nb] = (f32x4)0.0f;

    for (int kt = 0; kt < 16; ++kt) {
        const int k0 = kt * 32;
        if (BF16A) {
            const unsigned short* Eb = (const unsigned short*)Ein;
#pragma unroll
            for (int i = 0; i < 2; ++i) {
                const int r = (tid >> 2) + 64 * i;
                *(ushort8v*)&Al[r][(tid & 3) * 8] =
                    *(const ushort8v*)&Eb[(size_t)(row0 + r) * 512 + k0 + (tid & 3) * 8];
            }
        } else {
            const float* E = (const float*)Ein;
#pragma unroll
            for (int i = 0; i < 4; ++i) {
                const int r = (tid >> 3) + 32 * i;
                f32x4 v = *(const f32x4*)&E[(size_t)(row0 + r) * 512 + k0 + (tid & 7) * 4];
                ushort4v u;
#pragma unroll
                for (int j = 0; j < 4; ++j) u[j] = f2bf(v[j]);
                *(ushort4v*)&Al[r][(tid & 7) * 4] = u;
            }
        }
#pragma unroll
        for (int i = 0; i < BI; ++i) {
            const int kk = (tid / CPW) + KROWS * i;
            const int cc = (tid % CPW) * 4;
            f32x4 v = *(const f32x4*)&W[(size_t)(k0 + kk) * NC + c0 + cc];
#pragma unroll
            for (int j = 0; j < 4; ++j) Bl[cc + j][kk] = f2bf(v[j]);
        }
        __syncthreads();

        bf16x8 af[4], bw[NB];
#pragma unroll
        for (int mb = 0; mb < 4; ++mb) af[mb] = *(const bf16x8*)&Al[wm * 64 + mb * 16 + li][8 * g];
#pragma unroll
        for (int nb = 0; nb < NB; ++nb)
            bw[nb] = *(const bf16x8*)&Bl[wn * (BN / 2) + nb * 16 + li][8 * g];
#pragma unroll
        for (int mb = 0; mb < 4; ++mb)
#pragma unroll
            for (int nb = 0; nb < NB; ++nb) acc[mb][nb] = MFMA16(af[mb], bw[nb], acc[mb][nb]);
        __syncthreads();
    }

    float bv[NB];
#pragma unroll
    for (int nb = 0; nb < NB; ++nb) bv[nb] = bias[c0 + wn * (BN / 2) + nb * 16 + li];
#pragma unroll
    for (int mb = 0; mb < 4; ++mb) {
#pragma unroll
        for (int nb = 0; nb < NB; ++nb) {
            const int col = c0 + wn * (BN / 2) + nb * 16 + li;
            const int grow0 = row0 + wm * 64 + mb * 16 + 4 * g;
            if (TRV) {
                ushort4v u;
#pragma unroll
                for (int r = 0; r < 4; ++r) u[r] = f2bf((acc[mb][nb][r] + bv[nb]) * scale);
                const int bb = grow0 >> 12, n = grow0 & 4095;
                *(ushort4v*)(out + ((size_t)bb * 512 + col) * 4096 + n) = u;
            } else {
#pragma unroll
                for (int r = 0; r < 4; ++r)
                    out[(size_t)(grow0 + r) * NC + col] = f2bf((acc[mb][nb][r] + bv[nb]) * scale);
            }
        }
    }
}

template <bool BF16A>
__global__ __launch_bounds__(256) void proj_qk_kernel(const void* __restrict__ Ein,
        const float* __restrict__ wq, const float* __restrict__ bq, unsigned short* __restrict__ Qb,
        const float* __restrict__ wk, const float* __restrict__ bk, unsigned short* __restrict__ Kb)
{
    if (blockIdx.y == 0)
        proj_body<64, 64, false, BF16A>(Ein, wq, bq, Qb, 0.125f, blockIdx.x, 0);
    else
        proj_body<64, 64, false, BF16A>(Ein, wk, bk, Kb, 1.0f, blockIdx.x, 0);
}

template <bool BF16A>
__global__ __launch_bounds__(256) void proj_v_kernel(const void* __restrict__ Ein,
        const float* __restrict__ wv, const float* __restrict__ bv, unsigned short* __restrict__ Vt)
{
    proj_body<512, 128, true, BF16A>(Ein, wv, bv, Vt, 1.0f, blockIdx.x, blockIdx.y);
}

// ---------------------------------------------------------------------------
// Causal flash attention, v4: dual-stream + NON-DRAINING barriers.
// Inner barriers are lgkmcnt-only (LDS visibility); global K/V prefetches
// stay in flight across them and are waited only at their consumers.
// s_setprio(1) around MFMA clusters (T5).
// ---------------------------------------------------------------------------
__global__ __launch_bounds__(512, 4) void attn_kernel(const unsigned short* __restrict__ Qb,
                                                      const unsigned short* __restrict__ Kb,
                                                      const unsigned short* __restrict__ Vt,
                                                      float* __restrict__ out)
{
    __shared__ __align__(16) unsigned short Kl[2][2][64][64];  // [buf][tile][kv][d], chunk^row swizzle
    __shared__ __align__(16) unsigned short Pl[2][64][72];     // [grp][q][kv]
    __shared__ float pm2[2][64];
    __shared__ float rs2[64];
    __shared__ float scl_l[64];
    __shared__ float lsum_l[64];

    const int tid = threadIdx.x;
    const int w = tid >> 6, l = tid & 63, g = l >> 4, li = l & 15;
    const int grp = w >> 2, wq4 = w & 3;
    const int bid = blockIdx.x;
    const int t = bid >> 3, b = (bid >> 1) & 3, ch = bid & 1;
    const int qt = (t < 32) ? (63 - t) : (t - 32);
    const int q0 = qt * 64;
    const int niter = (qt >> 1) + 1;
    const int rowbase = 16 * wq4 + 4 * g;

    const unsigned short* qptr = Qb + ((size_t)(b * 4096 + q0 + 16 * wq4 + li)) * 64 + 8 * g;
    const bf16x8 QA0 = *(const bf16x8*)qptr;
    const bf16x8 QA1 = *(const bf16x8*)(qptr + 32);

    float m_r[4], l_r[4];
#pragma unroll
    for (int r = 0; r < 4; ++r) { m_r[r] = -INFINITY; l_r[r] = 0.0f; }

    f32x4 Of[4][2];
#pragma unroll
    for (int qb = 0; qb < 4; ++qb) { Of[qb][0] = (f32x4)0.0f; Of[qb][1] = (f32x4)0.0f; }

    const int cglob = ch * 256 + w * 32 + li;
    const unsigned short* vb2 = Vt + ((size_t)(b * 512 + cglob)) * 4096 + 8 * g;

    const int krow = tid >> 3, kch = tid & 7;
    const unsigned short* kgb = Kb + ((size_t)(b * 4096 + krow)) * 64 + kch * 8;
    const int kslot = (kch ^ (krow & 7)) * 8;

    {   // prologue: stage pair 0 into buf 0
        ushort8v v0 = *(const ushort8v*)(kgb);
        ushort8v v1 = *(const ushort8v*)(kgb + (size_t)imin(1, qt) * 4096);
        *(ushort8v*)&Kl[0][0][krow][kslot] = v0;
        *(ushort8v*)&Kl[0][1][krow][kslot] = v1;
    }
    ldsbar();

    for (int k = 0; k < niter; ++k) {
        const int buf = k & 1;
        const int tA = 2 * k, tB = 2 * k + 1;
        const bool actB = (tB <= qt);
        const int myt = grp ? tB : tA;
        const bool act = grp ? actB : true;

        // issue next-pair K global loads (landed into LDS before barrier 2)
        ushort8v kn0, kn1;
        const bool havenext = (k + 1 < niter);
        if (havenext) {
            kn0 = *(const ushort8v*)(kgb + (size_t)imin(2 * k + 2, qt) * 4096);
            kn1 = *(const ushort8v*)(kgb + (size_t)imin(2 * k + 3, qt) * 4096);
        }
        // issue this iteration's V loads (consumed in phase B; in flight across barriers)
        const size_t kvA = (size_t)tA * 64;
        const size_t kvB = (size_t)imin(tB, qt) * 64;
        bf16x8 VA[2][2], VBt[2][2];
#pragma unroll
        for (int cf = 0; cf < 2; ++cf)
#pragma unroll
            for (int ks = 0; ks < 2; ++ks) {
                VA[cf][ks] = *(const bf16x8*)(vb2 + (size_t)cf * 16 * 4096 + kvA + ks * 32);
                VBt[cf][ks] = *(const bf16x8*)(vb2 + (size_t)cf * 16 * 4096 + kvB + ks * 32);
            }

        // ---- phase A ----
        f32x4 S[4];
        float pm[4];
        if (act) {
            const unsigned short(*Kt)[64] = Kl[buf][grp];
            __builtin_amdgcn_s_setprio(1);
#pragma unroll
            for (int cb = 0; cb < 4; ++cb) {
                const int row = cb * 16 + li;
                bf16x8 K0 = *(const bf16x8*)&Kt[row][((g) ^ (row & 7)) * 8];
                bf16x8 K1 = *(const bf16x8*)&Kt[row][((4 + g) ^ (row & 7)) * 8];
                f32x4 s = (f32x4)0.0f;
                s = MFMA16(QA0, K0, s);
                s = MFMA16(QA1, K1, s);
                S[cb] = s;
            }
            __builtin_amdgcn_s_setprio(0);
            if (myt == qt) {
#pragma unroll
                for (int cb = 0; cb < 4; ++cb)
#pragma unroll
                    for (int r = 0; r < 4; ++r)
                        if (cb * 16 + li > rowbase + r) S[cb][r] = -1e30f;
            }
#pragma unroll
            for (int r = 0; r < 4; ++r)
                pm[r] = fmaxf(fmaxf(S[0][r], S[1][r]), fmaxf(S[2][r], S[3][r]));
#pragma unroll
            for (int d = 1; d < 16; d <<= 1)
#pragma unroll
                for (int r = 0; r < 4; ++r) pm[r] = fmaxf(pm[r], __shfl_xor(pm[r], d));
        } else {
#pragma unroll
            for (int r = 0; r < 4; ++r) pm[r] = -INFINITY;
        }
        if (li == 0) {
#pragma unroll
            for (int r = 0; r < 4; ++r) pm2[grp][rowbase + r] = pm[r];
        }
        ldsbar();  // barrier 1 (LDS-only)

        float sc[4];
#pragma unroll
        for (int r = 0; r < 4; ++r) {
            const float mn = fmaxf(m_r[r], fmaxf(pm2[0][rowbase + r], pm2[1][rowbase + r]));
            sc[r] = __expf(m_r[r] - mn);
            m_r[r] = mn;
        }
        if (grp == 0 && li == 0) {
#pragma unroll
            for (int r = 0; r < 4; ++r) scl_l[rowbase + r] = sc[r];
        }

        float rs[4] = {0.0f, 0.0f, 0.0f, 0.0f};
        if (act) {
#pragma unroll
            for (int cb = 0; cb < 4; ++cb)
#pragma unroll
                for (int r = 0; r < 4; ++r) {
                    const float p = __expf(S[cb][r] - m_r[r]);
                    rs[r] += p;
                    Pl[grp][rowbase + r][cb * 16 + li] = f2bf(p);
                }
#pragma unroll
            for (int d = 1; d < 16; d <<= 1)
#pragma unroll
                for (int r = 0; r < 4; ++r) rs[r] += __shfl_xor(rs[r], d);
        }
        if (grp == 1 && li == 0) {
#pragma unroll
            for (int r = 0; r < 4; ++r) rs2[rowbase + r] = rs[r];
        }

        // land next K pair (compiler waits vmcnt for kn just before these writes)
        if (havenext) {
            *(ushort8v*)&Kl[buf ^ 1][0][krow][kslot] = kn0;
            *(ushort8v*)&Kl[buf ^ 1][1][krow][kslot] = kn1;
        }
        ldsbar();  // barrier 2 (LDS-only)

        if (grp == 0) {
#pragma unroll
            for (int r = 0; r < 4; ++r) l_r[r] = l_r[r] * sc[r] + rs[r] + rs2[rowbase + r];
        }

        // ---- phase B: PV ----
        __builtin_amdgcn_s_setprio(1);
#pragma unroll
        for (int qb = 0; qb < 4; ++qb) {
            f32x4 scv = *(const f32x4*)&scl_l[qb * 16 + 4 * g];
            bf16x8 PA0 = *(const bf16x8*)&Pl[0][qb * 16 + li][8 * g];
            bf16x8 PA1 = *(const bf16x8*)&Pl[0][qb * 16 + li][32 + 8 * g];
#pragma unroll
            for (int cf = 0; cf < 2; ++cf) {
                f32x4 o = Of[qb][cf];
#pragma unroll
                for (int r = 0; r < 4; ++r) o[r] *= scv[r];
                o = MFMA16(PA0, VA[cf][0], o);
                o = MFMA16(PA1, VA[cf][1], o);
                Of[qb][cf] = o;
            }
            if (actB) {
                bf16x8 PB0 = *(const bf16x8*)&Pl[1][qb * 16 + li][8 * g];
                bf16x8 PB1 = *(const bf16x8*)&Pl[1][qb * 16 + li][32 + 8 * g];
#pragma unroll
                for (int cf = 0; cf < 2; ++cf) {
                    f32x4 o = Of[qb][cf];
                    o = MFMA16(PB0, VBt[cf][0], o);
                    o = MFMA16(PB1, VBt[cf][1], o);
                    Of[qb][cf] = o;
                }
            }
        }
        __builtin_amdgcn_s_setprio(0);
    }

    if (grp == 0 && li == 0) {
#pragma unroll
        for (int r = 0; r < 4; ++r) lsum_l[rowbase + r] = l_r[r];
    }
    ldsbar();

    float* obase = out + (size_t)(b * 4096 + q0 + 4 * g) * 512 + cglob;
#pragma unroll
    for (int qb = 0; qb < 4; ++qb) {
        f32x4 lv = *(const f32x4*)&lsum_l[qb * 16 + 4 * g];
#pragma unroll
        for (int cf = 0; cf < 2; ++cf)
#pragma unroll
            for (int r = 0; r < 4; ++r)
                obase[(size_t)(qb * 16 + r) * 512 + cf * 16] = Of[qb][cf][r] / lv[r];
    }
}

// ---------------------------------------------------------------------------
extern "C" void kernel_launch(void* const* d_in, const int* in_sizes, int n_in,
                              void* d_out, int out_size, void* d_ws, size_t ws_size,
                              hipStream_t stream)
{
    (void)in_sizes; (void)n_in; (void)out_size;
    const float* E  = (const float*)d_in[0];
    const float* wq = (const float*)d_in[2];
    const float* bq = (const float*)d_in[3];
    const float* wk = (const float*)d_in[4];
    const float* bk = (const float*)d_in[5];
    const float* wv = (const float*)d_in[6];
    const float* bv = (const float*)d_in[7];

    const size_t qk_elems = (size_t)4 * 4096 * 64;
    const size_t vt_elems = (size_t)4 * 512 * 4096;
    const size_t eb_elems = (size_t)4 * 4096 * 512;

    unsigned short* Qb = (unsigned short*)d_ws;
    unsigned short* Kb = Qb + qk_elems;
    unsigned short* Vt = Kb + qk_elems;
    unsigned short* Eb = Vt + vt_elems;
    float* out = (float*)d_out;

    const size_t need_bf16 = (2 * qk_elems + vt_elems + eb_elems) * sizeof(unsigned short);
    if (ws_size >= need_bf16) {
        conv_kernel<<<dim3(4096), 256, 0, stream>>>(E, Eb);
        proj_qk_kernel<true><<<dim3(128, 2), 256, 0, stream>>>(Eb, wq, bq, Qb, wk, bk, Kb);
        proj_v_kernel<true><<<dim3(128, 4), 256, 0, stream>>>(Eb, wv, bv, Vt);
    } else {
        proj_qk_kernel<false><<<dim3(128, 2), 256, 0, stream>>>(E, wq, bq, Qb, wk, bk, Kb);
        proj_v_kernel<false><<<dim3(128, 4), 256, 0, stream>>>(E, wv, bv, Vt);
    }
    attn_kernel<<<dim3(512), 512, 0, stream>>>(Qb, Kb, Vt, out);
}

// Round 5
// 218.637 us; speedup vs baseline: 1.2554x; 1.2554x over previous
//
#include <hip/hip_runtime.h>
#include <hip/hip_bf16.h>

typedef float f32x4 __attribute__((ext_vector_type(4)));
typedef __bf16 bf16x8 __attribute__((ext_vector_type(8)));
typedef unsigned short ushort4v __attribute__((ext_vector_type(4)));
typedef unsigned short ushort8v __attribute__((ext_vector_type(8)));

#define MFMA16(a, b, c) __builtin_amdgcn_mfma_f32_16x16x32_bf16((a), (b), (c), 0, 0, 0)

__device__ __forceinline__ unsigned short f2bf(float f) {
    union { float f; unsigned int u; } v; v.f = f;
    unsigned int r = (v.u + 0x7fffu + ((v.u >> 16) & 1u)) >> 16;  // RNE
    return (unsigned short)r;
}
__device__ __forceinline__ int imin(int a, int b) { return a < b ? a : b; }

// LDS-only barrier: flush this wave's LDS ops, then s_barrier.
// Does NOT drain vmcnt -> global prefetches stay in flight across it.
__device__ __forceinline__ void ldsbar() {
    asm volatile("s_waitcnt lgkmcnt(0)" ::: "memory");
    __builtin_amdgcn_s_barrier();
}

// ---------------------------------------------------------------------------
// E -> bf16 conversion (one pass).
// ---------------------------------------------------------------------------
__global__ __launch_bounds__(256) void conv_kernel(const float* __restrict__ E,
                                                   unsigned short* __restrict__ Eb)
{
    const size_t i = ((size_t)blockIdx.x * 256 + threadIdx.x) * 8;
    f32x4 a = *(const f32x4*)&E[i];
    f32x4 b = *(const f32x4*)&E[i + 4];
    ushort8v u;
#pragma unroll
    for (int j = 0; j < 4; ++j) { u[j] = f2bf(a[j]); u[4 + j] = f2bf(b[j]); }
    *(ushort8v*)&Eb[i] = u;
}

// ---------------------------------------------------------------------------
// Projection GEMM body. M=16384, K=512. BM=128 x BN, BK=32; 4 waves (2x2).
// ---------------------------------------------------------------------------
template <int NC, int BN, bool TRV, bool BF16A>
__device__ __forceinline__ void proj_body(const void* __restrict__ Ein,
                                          const float* __restrict__ W,
                                          const float* __restrict__ bias,
                                          unsigned short* __restrict__ out,
                                          float scale, int bx, int by)
{
    constexpr int NB = BN / 32;
    constexpr int CPW = BN / 4;
    constexpr int KROWS = 256 / CPW;
    constexpr int BI = 32 / KROWS;

    __shared__ __align__(16) unsigned short Al[128][40];
    __shared__ __align__(16) unsigned short Bl[BN][40];

    const int tid = threadIdx.x;
    const int w = tid >> 6, l = tid & 63, g = l >> 4, li = l & 15;
    const int wm = w >> 1, wn = w & 1;
    const int row0 = bx * 128;
    const int c0 = by * BN;

    f32x4 acc[4][NB];
#pragma unroll
    for (int mb = 0; mb < 4; ++mb)
#pragma unroll
        for (int nb = 0; nb < NB; ++nb) acc[mb][nb] = (f32x4)0.0f;

    for (int kt = 0; kt < 16; ++kt) {
        const int k0 = kt * 32;
        if (BF16A) {
            const unsigned short* Eb = (const unsigned short*)Ein;
#pragma unroll
            for (int i = 0; i < 2; ++i) {
                const int r = (tid >> 2) + 64 * i;
                *(ushort8v*)&Al[r][(tid & 3) * 8] =
                    *(const ushort8v*)&Eb[(size_t)(row0 + r) * 512 + k0 + (tid & 3) * 8];
            }
        } else {
            const float* E = (const float*)Ein;
#pragma unroll
            for (int i = 0; i < 4; ++i) {
                const int r = (tid >> 3) + 32 * i;
                f32x4 v = *(const f32x4*)&E[(size_t)(row0 + r) * 512 + k0 + (tid & 7) * 4];
                ushort4v u;
#pragma unroll
                for (int j = 0; j < 4; ++j) u[j] = f2bf(v[j]);
                *(ushort4v*)&Al[r][(tid & 7) * 4] = u;
            }
        }
#pragma unroll
        for (int i = 0; i < BI; ++i) {
            const int kk = (tid / CPW) + KROWS * i;
            const int cc = (tid % CPW) * 4;
            f32x4 v = *(const f32x4*)&W[(size_t)(k0 + kk) * NC + c0 + cc];
#pragma unroll
            for (int j = 0; j < 4; ++j) Bl[cc + j][kk] = f2bf(v[j]);
        }
        __syncthreads();

        bf16x8 af[4], bw[NB];
#pragma unroll
        for (int mb = 0; mb < 4; ++mb) af[mb] = *(const bf16x8*)&Al[wm * 64 + mb * 16 + li][8 * g];
#pragma unroll
        for (int nb = 0; nb < NB; ++nb)
            bw[nb] = *(const bf16x8*)&Bl[wn * (BN / 2) + nb * 16 + li][8 * g];
#pragma unroll
        for (int mb = 0; mb < 4; ++mb)
#pragma unroll
            for (int nb = 0; nb < NB; ++nb) acc[mb][nb] = MFMA16(af[mb], bw[nb], acc[mb][nb]);
        __syncthreads();
    }

    float bv[NB];
#pragma unroll
    for (int nb = 0; nb < NB; ++nb) bv[nb] = bias[c0 + wn * (BN / 2) + nb * 16 + li];
#pragma unroll
    for (int mb = 0; mb < 4; ++mb) {
#pragma unroll
        for (int nb = 0; nb < NB; ++nb) {
            const int col = c0 + wn * (BN / 2) + nb * 16 + li;
            const int grow0 = row0 + wm * 64 + mb * 16 + 4 * g;
            if (TRV) {
                ushort4v u;
#pragma unroll
                for (int r = 0; r < 4; ++r) u[r] = f2bf((acc[mb][nb][r] + bv[nb]) * scale);
                const int bb = grow0 >> 12, n = grow0 & 4095;
                *(ushort4v*)(out + ((size_t)bb * 512 + col) * 4096 + n) = u;
            } else {
#pragma unroll
                for (int r = 0; r < 4; ++r)
                    out[(size_t)(grow0 + r) * NC + col] = f2bf((acc[mb][nb][r] + bv[nb]) * scale);
            }
        }
    }
}

template <bool BF16A>
__global__ __launch_bounds__(256) void proj_qk_kernel(const void* __restrict__ Ein,
        const float* __restrict__ wq, const float* __restrict__ bq, unsigned short* __restrict__ Qb,
        const float* __restrict__ wk, const float* __restrict__ bk, unsigned short* __restrict__ Kb)
{
    if (blockIdx.y == 0)
        proj_body<64, 64, false, BF16A>(Ein, wq, bq, Qb, 0.125f, blockIdx.x, 0);
    else
        proj_body<64, 64, false, BF16A>(Ein, wk, bk, Kb, 1.0f, blockIdx.x, 0);
}

template <bool BF16A>
__global__ __launch_bounds__(256) void proj_v_kernel(const void* __restrict__ Ein,
        const float* __restrict__ wv, const float* __restrict__ bv, unsigned short* __restrict__ Vt)
{
    proj_body<512, 128, true, BF16A>(Ein, wv, bv, Vt, 1.0f, blockIdx.x, blockIdx.y);
}

// ---------------------------------------------------------------------------
// Causal flash attention, v5: dual-stream + non-draining barriers + setprio,
// WITHOUT the round-3 launch-bounds register cap (that forced 64 VGPRs and
// ~73 MB/dispatch of scratch spill traffic -- the real round-3/4 bottleneck).
// ---------------------------------------------------------------------------
__global__ __launch_bounds__(512) void attn_kernel(const unsigned short* __restrict__ Qb,
                                                   const unsigned short* __restrict__ Kb,
                                                   const unsigned short* __restrict__ Vt,
                                                   float* __restrict__ out)
{
    __shared__ __align__(16) unsigned short Kl[2][2][64][64];  // [buf][tile][kv][d], chunk^row swizzle
    __shared__ __align__(16) unsigned short Pl[2][64][72];     // [grp][q][kv]
    __shared__ float pm2[2][64];
    __shared__ float rs2[64];
    __shared__ float scl_l[64];
    __shared__ float lsum_l[64];

    const int tid = threadIdx.x;
    const int w = tid >> 6, l = tid & 63, g = l >> 4, li = l & 15;
    const int grp = w >> 2, wq4 = w & 3;
    const int bid = blockIdx.x;
    const int t = bid >> 3, b = (bid >> 1) & 3, ch = bid & 1;
    const int qt = (t < 32) ? (63 - t) : (t - 32);
    const int q0 = qt * 64;
    const int niter = (qt >> 1) + 1;
    const int rowbase = 16 * wq4 + 4 * g;

    const unsigned short* qptr = Qb + ((size_t)(b * 4096 + q0 + 16 * wq4 + li)) * 64 + 8 * g;
    const bf16x8 QA0 = *(const bf16x8*)qptr;
    const bf16x8 QA1 = *(const bf16x8*)(qptr + 32);

    float m_r[4], l_r[4];
#pragma unroll
    for (int r = 0; r < 4; ++r) { m_r[r] = -INFINITY; l_r[r] = 0.0f; }

    f32x4 Of[4][2];
#pragma unroll
    for (int qb = 0; qb < 4; ++qb) { Of[qb][0] = (f32x4)0.0f; Of[qb][1] = (f32x4)0.0f; }

    const int cglob = ch * 256 + w * 32 + li;
    const unsigned short* vb2 = Vt + ((size_t)(b * 512 + cglob)) * 4096 + 8 * g;

    const int krow = tid >> 3, kch = tid & 7;
    const unsigned short* kgb = Kb + ((size_t)(b * 4096 + krow)) * 64 + kch * 8;
    const int kslot = (kch ^ (krow & 7)) * 8;

    {   // prologue: stage pair 0 into buf 0
        ushort8v v0 = *(const ushort8v*)(kgb);
        ushort8v v1 = *(const ushort8v*)(kgb + (size_t)imin(1, qt) * 4096);
        *(ushort8v*)&Kl[0][0][krow][kslot] = v0;
        *(ushort8v*)&Kl[0][1][krow][kslot] = v1;
    }
    ldsbar();

    for (int k = 0; k < niter; ++k) {
        const int buf = k & 1;
        const int tA = 2 * k, tB = 2 * k + 1;
        const bool actB = (tB <= qt);
        const int myt = grp ? tB : tA;
        const bool act = grp ? actB : true;

        // issue next-pair K global loads (landed into LDS before barrier 2)
        ushort8v kn0, kn1;
        const bool havenext = (k + 1 < niter);
        if (havenext) {
            kn0 = *(const ushort8v*)(kgb + (size_t)imin(2 * k + 2, qt) * 4096);
            kn1 = *(const ushort8v*)(kgb + (size_t)imin(2 * k + 3, qt) * 4096);
        }
        // issue this iteration's V loads (consumed in phase B; in flight across barriers)
        const size_t kvA = (size_t)tA * 64;
        const size_t kvB = (size_t)imin(tB, qt) * 64;
        bf16x8 VA[2][2], VBt[2][2];
#pragma unroll
        for (int cf = 0; cf < 2; ++cf)
#pragma unroll
            for (int ks = 0; ks < 2; ++ks) {
                VA[cf][ks] = *(const bf16x8*)(vb2 + (size_t)cf * 16 * 4096 + kvA + ks * 32);
                VBt[cf][ks] = *(const bf16x8*)(vb2 + (size_t)cf * 16 * 4096 + kvB + ks * 32);
            }

        // ---- phase A ----
        f32x4 S[4];
        float pm[4];
        if (act) {
            const unsigned short(*Kt)[64] = Kl[buf][grp];
            __builtin_amdgcn_s_setprio(1);
#pragma unroll
            for (int cb = 0; cb < 4; ++cb) {
                const int row = cb * 16 + li;
                bf16x8 K0 = *(const bf16x8*)&Kt[row][((g) ^ (row & 7)) * 8];
                bf16x8 K1 = *(const bf16x8*)&Kt[row][((4 + g) ^ (row & 7)) * 8];
                f32x4 s = (f32x4)0.0f;
                s = MFMA16(QA0, K0, s);
                s = MFMA16(QA1, K1, s);
                S[cb] = s;
            }
            __builtin_amdgcn_s_setprio(0);
            if (myt == qt) {
#pragma unroll
                for (int cb = 0; cb < 4; ++cb)
#pragma unroll
                    for (int r = 0; r < 4; ++r)
                        if (cb * 16 + li > rowbase + r) S[cb][r] = -1e30f;
            }
#pragma unroll
            for (int r = 0; r < 4; ++r)
                pm[r] = fmaxf(fmaxf(S[0][r], S[1][r]), fmaxf(S[2][r], S[3][r]));
#pragma unroll
            for (int d = 1; d < 16; d <<= 1)
#pragma unroll
                for (int r = 0; r < 4; ++r) pm[r] = fmaxf(pm[r], __shfl_xor(pm[r], d));
        } else {
#pragma unroll
            for (int r = 0; r < 4; ++r) pm[r] = -INFINITY;
        }
        if (li == 0) {
#pragma unroll
            for (int r = 0; r < 4; ++r) pm2[grp][rowbase + r] = pm[r];
        }
        ldsbar();  // barrier 1 (LDS-only)

        float sc[4];
#pragma unroll
        for (int r = 0; r < 4; ++r) {
            const float mn = fmaxf(m_r[r], fmaxf(pm2[0][rowbase + r], pm2[1][rowbase + r]));
            sc[r] = __expf(m_r[r] - mn);
            m_r[r] = mn;
        }
        if (grp == 0 && li == 0) {
#pragma unroll
            for (int r = 0; r < 4; ++r) scl_l[rowbase + r] = sc[r];
        }

        float rs[4] = {0.0f, 0.0f, 0.0f, 0.0f};
        if (act) {
#pragma unroll
            for (int cb = 0; cb < 4; ++cb)
#pragma unroll
                for (int r = 0; r < 4; ++r) {
                    const float p = __expf(S[cb][r] - m_r[r]);
                    rs[r] += p;
                    Pl[grp][rowbase + r][cb * 16 + li] = f2bf(p);
                }
#pragma unroll
            for (int d = 1; d < 16; d <<= 1)
#pragma unroll
                for (int r = 0; r < 4; ++r) rs[r] += __shfl_xor(rs[r], d);
        }
        if (grp == 1 && li == 0) {
#pragma unroll
            for (int r = 0; r < 4; ++r) rs2[rowbase + r] = rs[r];
        }

        // land next K pair (compiler waits vmcnt for kn just before these writes)
        if (havenext) {
            *(ushort8v*)&Kl[buf ^ 1][0][krow][kslot] = kn0;
            *(ushort8v*)&Kl[buf ^ 1][1][krow][kslot] = kn1;
        }
        ldsbar();  // barrier 2 (LDS-only)

        if (grp == 0) {
#pragma unroll
            for (int r = 0; r < 4; ++r) l_r[r] = l_r[r] * sc[r] + rs[r] + rs2[rowbase + r];
        }

        // ---- phase B: PV ----
        __builtin_amdgcn_s_setprio(1);
#pragma unroll
        for (int qb = 0; qb < 4; ++qb) {
            f32x4 scv = *(const f32x4*)&scl_l[qb * 16 + 4 * g];
            bf16x8 PA0 = *(const bf16x8*)&Pl[0][qb * 16 + li][8 * g];
            bf16x8 PA1 = *(const bf16x8*)&Pl[0][qb * 16 + li][32 + 8 * g];
#pragma unroll
            for (int cf = 0; cf < 2; ++cf) {
                f32x4 o = Of[qb][cf];
#pragma unroll
                for (int r = 0; r < 4; ++r) o[r] *= scv[r];
                o = MFMA16(PA0, VA[cf][0], o);
                o = MFMA16(PA1, VA[cf][1], o);
                Of[qb][cf] = o;
            }
            if (actB) {
                bf16x8 PB0 = *(const bf16x8*)&Pl[1][qb * 16 + li][8 * g];
                bf16x8 PB1 = *(const bf16x8*)&Pl[1][qb * 16 + li][32 + 8 * g];
#pragma unroll
                for (int cf = 0; cf < 2; ++cf) {
                    f32x4 o = Of[qb][cf];
                    o = MFMA16(PB0, VBt[cf][0], o);
                    o = MFMA16(PB1, VBt[cf][1], o);
                    Of[qb][cf] = o;
                }
            }
        }
        __builtin_amdgcn_s_setprio(0);
    }

    if (grp == 0 && li == 0) {
#pragma unroll
        for (int r = 0; r < 4; ++r) lsum_l[rowbase + r] = l_r[r];
    }
    ldsbar();

    float* obase = out + (size_t)(b * 4096 + q0 + 4 * g) * 512 + cglob;
#pragma unroll
    for (int qb = 0; qb < 4; ++qb) {
        f32x4 lv = *(const f32x4*)&lsum_l[qb * 16 + 4 * g];
#pragma unroll
        for (int cf = 0; cf < 2; ++cf)
#pragma unroll
            for (int r = 0; r < 4; ++r)
                obase[(size_t)(qb * 16 + r) * 512 + cf * 16] = Of[qb][cf][r] / lv[r];
    }
}

// ---------------------------------------------------------------------------
extern "C" void kernel_launch(void* const* d_in, const int* in_sizes, int n_in,
                              void* d_out, int out_size, void* d_ws, size_t ws_size,
                              hipStream_t stream)
{
    (void)in_sizes; (void)n_in; (void)out_size;
    const float* E  = (const float*)d_in[0];
    const float* wq = (const float*)d_in[2];
    const float* bq = (const float*)d_in[3];
    const float* wk = (const float*)d_in[4];
    const float* bk = (const float*)d_in[5];
    const float* wv = (const float*)d_in[6];
    const float* bv = (const float*)d_in[7];

    const size_t qk_elems = (size_t)4 * 4096 * 64;
    const size_t vt_elems = (size_t)4 * 512 * 4096;
    const size_t eb_elems = (size_t)4 * 4096 * 512;

    unsigned short* Qb = (unsigned short*)d_ws;
    unsigned short* Kb = Qb + qk_elems;
    unsigned short* Vt = Kb + qk_elems;
    unsigned short* Eb = Vt + vt_elems;
    float* out = (float*)d_out;

    const size_t need_bf16 = (2 * qk_elems + vt_elems + eb_elems) * sizeof(unsigned short);
    if (ws_size >= need_bf16) {
        conv_kernel<<<dim3(4096), 256, 0, stream>>>(E, Eb);
        proj_qk_kernel<true><<<dim3(128, 2), 256, 0, stream>>>(Eb, wq, bq, Qb, wk, bk, Kb);
        proj_v_kernel<true><<<dim3(128, 4), 256, 0, stream>>>(Eb, wv, bv, Vt);
    } else {
        proj_qk_kernel<false><<<dim3(128, 2), 256, 0, stream>>>(E, wq, bq, Qb, wk, bk, Kb);
        proj_v_kernel<false><<<dim3(128, 4), 256, 0, stream>>>(E, wv, bv, Vt);
    }
    attn_kernel<<<dim3(512), 512, 0, stream>>>(Qb, Kb, Vt, out);
}

// Round 6
// 192.123 us; speedup vs baseline: 1.4286x; 1.1380x over previous
//
#include <hip/hip_runtime.h>
#include <hip/hip_bf16.h>

typedef float f32x4 __attribute__((ext_vector_type(4)));
typedef __bf16 bf16x8 __attribute__((ext_vector_type(8)));
typedef __bf16 bf16x4 __attribute__((ext_vector_type(4)));
typedef unsigned short ushort4v __attribute__((ext_vector_type(4)));
typedef unsigned short ushort8v __attribute__((ext_vector_type(8)));

#define MFMA16(a, b, c) __builtin_amdgcn_mfma_f32_16x16x32_bf16((a), (b), (c), 0, 0, 0)

__device__ __forceinline__ unsigned short f2bf(float f) {
    union { float f; unsigned int u; } v; v.f = f;
    unsigned int r = (v.u + 0x7fffu + ((v.u >> 16) & 1u)) >> 16;  // RNE
    return (unsigned short)r;
}
__device__ __forceinline__ int imin(int a, int b) { return a < b ? a : b; }

// LDS-only barrier: flush this wave's LDS ops, then s_barrier (no vmcnt drain).
__device__ __forceinline__ void ldsbar() {
    asm volatile("s_waitcnt lgkmcnt(0)" ::: "memory");
    __builtin_amdgcn_s_barrier();
}

// ---------------------------------------------------------------------------
// E -> bf16 conversion (one pass).
// ---------------------------------------------------------------------------
__global__ __launch_bounds__(256) void conv_kernel(const float* __restrict__ E,
                                                   unsigned short* __restrict__ Eb)
{
    const size_t i = ((size_t)blockIdx.x * 256 + threadIdx.x) * 8;
    f32x4 a = *(const f32x4*)&E[i];
    f32x4 b = *(const f32x4*)&E[i + 4];
    ushort8v u;
#pragma unroll
    for (int j = 0; j < 4; ++j) { u[j] = f2bf(a[j]); u[4 + j] = f2bf(b[j]); }
    *(ushort8v*)&Eb[i] = u;
}

// ---------------------------------------------------------------------------
// Projection GEMM body. M=16384, K=512. BM=128 x BN, BK=32; 4 waves (2x2).
// ---------------------------------------------------------------------------
template <int NC, int BN, bool TRV, bool BF16A>
__device__ __forceinline__ void proj_body(const void* __restrict__ Ein,
                                          const float* __restrict__ W,
                                          const float* __restrict__ bias,
                                          unsigned short* __restrict__ out,
                                          float scale, int bx, int by)
{
    constexpr int NB = BN / 32;
    constexpr int CPW = BN / 4;
    constexpr int KROWS = 256 / CPW;
    constexpr int BI = 32 / KROWS;

    __shared__ __align__(16) unsigned short Al[128][40];
    __shared__ __align__(16) unsigned short Bl[BN][40];

    const int tid = threadIdx.x;
    const int w = tid >> 6, l = tid & 63, g = l >> 4, li = l & 15;
    const int wm = w >> 1, wn = w & 1;
    const int row0 = bx * 128;
    const int c0 = by * BN;

    f32x4 acc[4][NB];
#pragma unroll
    for (int mb = 0; mb < 4; ++mb)
#pragma unroll
        for (int nb = 0; nb < NB; ++nb) acc[mb][nb] = (f32x4)0.0f;

    for (int kt = 0; kt < 16; ++kt) {
        const int k0 = kt * 32;
        if (BF16A) {
            const unsigned short* Eb = (const unsigned short*)Ein;
#pragma unroll
            for (int i = 0; i < 2; ++i) {
                const int r = (tid >> 2) + 64 * i;
                *(ushort8v*)&Al[r][(tid & 3) * 8] =
                    *(const ushort8v*)&Eb[(size_t)(row0 + r) * 512 + k0 + (tid & 3) * 8];
            }
        } else {
            const float* E = (const float*)Ein;
#pragma unroll
            for (int i = 0; i < 4; ++i) {
                const int r = (tid >> 3) + 32 * i;
                f32x4 v = *(const f32x4*)&E[(size_t)(row0 + r) * 512 + k0 + (tid & 7) * 4];
                ushort4v u;
#pragma unroll
                for (int j = 0; j < 4; ++j) u[j] = f2bf(v[j]);
                *(ushort4v*)&Al[r][(tid & 7) * 4] = u;
            }
        }
#pragma unroll
        for (int i = 0; i < BI; ++i) {
            const int kk = (tid / CPW) + KROWS * i;
            const int cc = (tid % CPW) * 4;
            f32x4 v = *(const f32x4*)&W[(size_t)(k0 + kk) * NC + c0 + cc];
#pragma unroll
            for (int j = 0; j < 4; ++j) Bl[cc + j][kk] = f2bf(v[j]);
        }
        __syncthreads();

        bf16x8 af[4], bw[NB];
#pragma unroll
        for (int mb = 0; mb < 4; ++mb) af[mb] = *(const bf16x8*)&Al[wm * 64 + mb * 16 + li][8 * g];
#pragma unroll
        for (int nb = 0; nb < NB; ++nb)
            bw[nb] = *(const bf16x8*)&Bl[wn * (BN / 2) + nb * 16 + li][8 * g];
#pragma unroll
        for (int mb = 0; mb < 4; ++mb)
#pragma unroll
            for (int nb = 0; nb < NB; ++nb) acc[mb][nb] = MFMA16(af[mb], bw[nb], acc[mb][nb]);
        __syncthreads();
    }

    float bv[NB];
#pragma unroll
    for (int nb = 0; nb < NB; ++nb) bv[nb] = bias[c0 + wn * (BN / 2) + nb * 16 + li];
#pragma unroll
    for (int mb = 0; mb < 4; ++mb) {
#pragma unroll
        for (int nb = 0; nb < NB; ++nb) {
            const int col = c0 + wn * (BN / 2) + nb * 16 + li;
            const int grow0 = row0 + wm * 64 + mb * 16 + 4 * g;
            if (TRV) {
                ushort4v u;
#pragma unroll
                for (int r = 0; r < 4; ++r) u[r] = f2bf((acc[mb][nb][r] + bv[nb]) * scale);
                const int bb = grow0 >> 12, n = grow0 & 4095;
                *(ushort4v*)(out + ((size_t)bb * 512 + col) * 4096 + n) = u;
            } else {
#pragma unroll
                for (int r = 0; r < 4; ++r)
                    out[(size_t)(grow0 + r) * NC + col] = f2bf((acc[mb][nb][r] + bv[nb]) * scale);
            }
        }
    }
}

template <bool BF16A>
__global__ __launch_bounds__(256) void proj_qk_kernel(const void* __restrict__ Ein,
        const float* __restrict__ wq, const float* __restrict__ bq, unsigned short* __restrict__ Qb,
        const float* __restrict__ wk, const float* __restrict__ bk, unsigned short* __restrict__ Kb)
{
    if (blockIdx.y == 0)
        proj_body<64, 64, false, BF16A>(Ein, wq, bq, Qb, 0.125f, blockIdx.x, 0);
    else
        proj_body<64, 64, false, BF16A>(Ein, wk, bk, Kb, 1.0f, blockIdx.x, 0);
}

template <bool BF16A>
__global__ __launch_bounds__(256) void proj_v_kernel(const void* __restrict__ Ein,
        const float* __restrict__ wv, const float* __restrict__ bv, unsigned short* __restrict__ Vt)
{
    proj_body<512, 128, true, BF16A>(Ein, wv, bv, Vt, 1.0f, blockIdx.x, blockIdx.y);
}

// ---------------------------------------------------------------------------
// Causal flash attention, v6: SWAPPED QK^T (S^T = mfma(K, Q)) so the kv
// reduction axis is lane-local: row max/sum = in-lane trees + 2 shfl_xor
// (was 32 ds-pipe shuffle ops), and P-writes are 4x ds_write_b64 (was 16x
// ds_write_b16). Attacks the measured LDS-pipe throughput bound.
// Dual-stream (2x64 kv tiles/iter), K LDS double-buffer, V reg prefetch,
// non-draining barriers, qt-paired dispatch.
// ---------------------------------------------------------------------------
__global__ __launch_bounds__(512) void attn_kernel(const unsigned short* __restrict__ Qb,
                                                   const unsigned short* __restrict__ Kb,
                                                   const unsigned short* __restrict__ Vt,
                                                   float* __restrict__ out)
{
    __shared__ __align__(16) unsigned short Kl[2][2][64][64];  // [buf][tile][kv][d], chunk^row swizzle
    __shared__ __align__(16) unsigned short Pl[2][64][72];     // [grp][q][kv]
    __shared__ float pm2[2][64];
    __shared__ float rs2[64];
    __shared__ float scl_l[64];
    __shared__ float lsum_l[64];

    const int tid = threadIdx.x;
    const int w = tid >> 6, l = tid & 63, g = l >> 4, li = l & 15;
    const int grp = w >> 2, wq4 = w & 3;
    const int bid = blockIdx.x;
    const int t = bid >> 3, b = (bid >> 1) & 3, ch = bid & 1;
    const int qt = (t < 32) ? (63 - t) : (t - 32);
    const int q0 = qt * 64;
    const int niter = (qt >> 1) + 1;
    const int qrow = 16 * wq4 + li;  // tile-local q row owned by this lane in phase A

    // Q fragment (acts as the MFMA B operand in swapped mode; same loads)
    const unsigned short* qptr = Qb + ((size_t)(b * 4096 + q0 + qrow)) * 64 + 8 * g;
    const bf16x8 QA0 = *(const bf16x8*)qptr;
    const bf16x8 QA1 = *(const bf16x8*)(qptr + 32);

    float m_r = -INFINITY, l_r = 0.0f;

    f32x4 Of[4][2];
#pragma unroll
    for (int qb = 0; qb < 4; ++qb) { Of[qb][0] = (f32x4)0.0f; Of[qb][1] = (f32x4)0.0f; }

    const int cglob = ch * 256 + w * 32 + li;
    const unsigned short* vb2 = Vt + ((size_t)(b * 512 + cglob)) * 4096 + 8 * g;

    const int krow = tid >> 3, kch = tid & 7;
    const unsigned short* kgb = Kb + ((size_t)(b * 4096 + krow)) * 64 + kch * 8;
    const int kslot = (kch ^ (krow & 7)) * 8;

    {   // prologue: stage kv-pair 0 into buf 0
        ushort8v v0 = *(const ushort8v*)(kgb);
        ushort8v v1 = *(const ushort8v*)(kgb + (size_t)imin(1, qt) * 4096);
        *(ushort8v*)&Kl[0][0][krow][kslot] = v0;
        *(ushort8v*)&Kl[0][1][krow][kslot] = v1;
    }
    ldsbar();

    for (int k = 0; k < niter; ++k) {
        const int buf = k & 1;
        const int tA = 2 * k, tB = 2 * k + 1;
        const bool actB = (tB <= qt);
        const int myt = grp ? tB : tA;
        const bool act = grp ? actB : true;

        // next-pair K global loads (stay in flight across barrier 1)
        ushort8v kn0, kn1;
        const bool havenext = (k + 1 < niter);
        if (havenext) {
            kn0 = *(const ushort8v*)(kgb + (size_t)imin(2 * k + 2, qt) * 4096);
            kn1 = *(const ushort8v*)(kgb + (size_t)imin(2 * k + 3, qt) * 4096);
        }
        // this iteration's V loads (consumed in phase B)
        const size_t kvA = (size_t)tA * 64;
        const size_t kvB = (size_t)imin(tB, qt) * 64;
        bf16x8 VA[2][2], VBt[2][2];
#pragma unroll
        for (int cf = 0; cf < 2; ++cf)
#pragma unroll
            for (int ks = 0; ks < 2; ++ks) {
                VA[cf][ks] = *(const bf16x8*)(vb2 + (size_t)cf * 16 * 4096 + kvA + ks * 32);
                VBt[cf][ks] = *(const bf16x8*)(vb2 + (size_t)cf * 16 * 4096 + kvB + ks * 32);
            }

        // ---- phase A (swapped): S^T[kv][q], kv lane-local ----
        f32x4 S[4];
        float pm;
        if (act) {
            const unsigned short(*Kt)[64] = Kl[buf][grp];
            __builtin_amdgcn_s_setprio(1);
#pragma unroll
            for (int cb = 0; cb < 4; ++cb) {
                const int row = cb * 16 + li;
                bf16x8 K0 = *(const bf16x8*)&Kt[row][((g) ^ (row & 7)) * 8];
                bf16x8 K1 = *(const bf16x8*)&Kt[row][((4 + g) ^ (row & 7)) * 8];
                f32x4 s = (f32x4)0.0f;
                s = MFMA16(K0, QA0, s);   // A = K, B = Q  ->  D = S^T
                s = MFMA16(K1, QA1, s);
                S[cb] = s;
            }
            __builtin_amdgcn_s_setprio(0);
            if (myt == qt) {  // diagonal tile: mask kv > q
#pragma unroll
                for (int cb = 0; cb < 4; ++cb)
#pragma unroll
                    for (int r = 0; r < 4; ++r)
                        if (cb * 16 + 4 * g + r > qrow) S[cb][r] = -1e30f;
            }
            // in-lane max over this lane's 16 kv values
            f32x4 m4 = S[0];
#pragma unroll
            for (int cb = 1; cb < 4; ++cb)
#pragma unroll
                for (int r = 0; r < 4; ++r) m4[r] = fmaxf(m4[r], S[cb][r]);
            pm = fmaxf(fmaxf(m4[0], m4[1]), fmaxf(m4[2], m4[3]));
            // combine the 4 lanes (g groups) sharing this q
            pm = fmaxf(pm, __shfl_xor(pm, 16));
            pm = fmaxf(pm, __shfl_xor(pm, 32));
        } else {
            pm = -INFINITY;
        }
        if (g == 0) pm2[grp][qrow] = pm;
        ldsbar();  // barrier 1 (LDS-only)

        const float mn = fmaxf(m_r, fmaxf(pm2[0][qrow], pm2[1][qrow]));
        const float sc = __expf(m_r - mn);
        m_r = mn;
        if (grp == 0 && g == 0) scl_l[qrow] = sc;

        float rs = 0.0f;
        if (act) {
#pragma unroll
            for (int cb = 0; cb < 4; ++cb) {
                bf16x4 pk;
#pragma unroll
                for (int r = 0; r < 4; ++r) {
                    const float pv = __expf(S[cb][r] - mn);
                    rs += pv;
                    pk[r] = (__bf16)pv;
                }
                *(bf16x4*)&Pl[grp][qrow][cb * 16 + 4 * g] = pk;  // ds_write_b64
            }
            rs += __shfl_xor(rs, 16);
            rs += __shfl_xor(rs, 32);
        }
        if (grp == 1 && g == 0) rs2[qrow] = rs;

        // land next K pair into the other buffer
        if (havenext) {
            *(ushort8v*)&Kl[buf ^ 1][0][krow][kslot] = kn0;
            *(ushort8v*)&Kl[buf ^ 1][1][krow][kslot] = kn1;
        }
        ldsbar();  // barrier 2 (LDS-only)

        if (grp == 0) l_r = l_r * sc + rs + rs2[qrow];

        // ---- phase B: PV (unchanged) ----
        __builtin_amdgcn_s_setprio(1);
#pragma unroll
        for (int qb = 0; qb < 4; ++qb) {
            f32x4 scv = *(const f32x4*)&scl_l[qb * 16 + 4 * g];
            bf16x8 PA0 = *(const bf16x8*)&Pl[0][qb * 16 + li][8 * g];
            bf16x8 PA1 = *(const bf16x8*)&Pl[0][qb * 16 + li][32 + 8 * g];
#pragma unroll
            for (int cf = 0; cf < 2; ++cf) {
                f32x4 o = Of[qb][cf];
#pragma unroll
                for (int r = 0; r < 4; ++r) o[r] *= scv[r];
                o = MFMA16(PA0, VA[cf][0], o);
                o = MFMA16(PA1, VA[cf][1], o);
                Of[qb][cf] = o;
            }
            if (actB) {
                bf16x8 PB0 = *(const bf16x8*)&Pl[1][qb * 16 + li][8 * g];
                bf16x8 PB1 = *(const bf16x8*)&Pl[1][qb * 16 + li][32 + 8 * g];
#pragma unroll
                for (int cf = 0; cf < 2; ++cf) {
                    f32x4 o = Of[qb][cf];
                    o = MFMA16(PB0, VBt[cf][0], o);
                    o = MFMA16(PB1, VBt[cf][1], o);
                    Of[qb][cf] = o;
                }
            }
        }
        __builtin_amdgcn_s_setprio(0);
    }

    if (grp == 0 && g == 0) lsum_l[qrow] = l_r;
    ldsbar();

    float* obase = out + (size_t)(b * 4096 + q0 + 4 * g) * 512 + cglob;
#pragma unroll
    for (int qb = 0; qb < 4; ++qb) {
        f32x4 lv = *(const f32x4*)&lsum_l[qb * 16 + 4 * g];
#pragma unroll
        for (int cf = 0; cf < 2; ++cf)
#pragma unroll
            for (int r = 0; r < 4; ++r)
                obase[(size_t)(qb * 16 + r) * 512 + cf * 16] = Of[qb][cf][r] / lv[r];
    }
}

// ---------------------------------------------------------------------------
extern "C" void kernel_launch(void* const* d_in, const int* in_sizes, int n_in,
                              void* d_out, int out_size, void* d_ws, size_t ws_size,
                              hipStream_t stream)
{
    (void)in_sizes; (void)n_in; (void)out_size;
    const float* E  = (const float*)d_in[0];
    const float* wq = (const float*)d_in[2];
    const float* bq = (const float*)d_in[3];
    const float* wk = (const float*)d_in[4];
    const float* bk = (const float*)d_in[5];
    const float* wv = (const float*)d_in[6];
    const float* bv = (const float*)d_in[7];

    const size_t qk_elems = (size_t)4 * 4096 * 64;
    const size_t vt_elems = (size_t)4 * 512 * 4096;
    const size_t eb_elems = (size_t)4 * 4096 * 512;

    unsigned short* Qb = (unsigned short*)d_ws;
    unsigned short* Kb = Qb + qk_elems;
    unsigned short* Vt = Kb + qk_elems;
    unsigned short* Eb = Vt + vt_elems;
    float* out = (float*)d_out;

    const size_t need_bf16 = (2 * qk_elems + vt_elems + eb_elems) * sizeof(unsigned short);
    if (ws_size >= need_bf16) {
        conv_kernel<<<dim3(4096), 256, 0, stream>>>(E, Eb);
        proj_qk_kernel<true><<<dim3(128, 2), 256, 0, stream>>>(Eb, wq, bq, Qb, wk, bk, Kb);
        proj_v_kernel<true><<<dim3(128, 4), 256, 0, stream>>>(Eb, wv, bv, Vt);
    } else {
        proj_qk_kernel<false><<<dim3(128, 2), 256, 0, stream>>>(E, wq, bq, Qb, wk, bk, Kb);
        proj_v_kernel<false><<<dim3(128, 4), 256, 0, stream>>>(E, wv, bv, Vt);
    }
    attn_kernel<<<dim3(512), 512, 0, stream>>>(Qb, Kb, Vt, out);
}